// Round 13
// baseline (278.081 us; speedup 1.0000x reference)
//
#include <hip/hip_runtime.h>

#define HID 256
#define NB 1024
#define NACT 16

typedef __bf16 bf16x8 __attribute__((ext_vector_type(8)));
typedef float  f32x4  __attribute__((ext_vector_type(4)));

// LDS: hA hi 32K | hA lo 32K | overlay 7K (Sp 4K | Sf 1K | Tp 2K). Total 71 KB.
#define HA_LO   32768
#define OV      65536
#define LDS_TOT 72704

#define PREP_N (4 * 65536 + 4096)

__device__ __forceinline__ unsigned short f2bf(float x) {
    union { __bf16 b; unsigned short u; } v; v.b = (__bf16)x; return v.u;
}
__device__ __forceinline__ float bf2f(unsigned short u) {
    union { unsigned short u; __bf16 b; } v; v.u = u; return (float)v.b;
}
__device__ __forceinline__ float b2f_lo(unsigned v) { return bf2f((unsigned short)(v & 0xffffu)); }
__device__ __forceinline__ float b2f_hi(unsigned v) { return bf2f((unsigned short)(v >> 16)); }
__device__ __forceinline__ unsigned pack2(float a, float b) {
    return (unsigned)f2bf(a) | ((unsigned)f2bf(b) << 16);
}

// ---- prep: WA/WH/WB in MFMA FRAGMENT ORDER [kq][nb][lane][8] (hi/lo pairs);
//      WD [a=16][k=256] pairs; Wc f32 [k][n] ----
// frag element: n = nb*16 + (lane&15), k = kq*32 + (lane>>4)*8 + e
__global__ __launch_bounds__(256) void prep_k(const float* __restrict__ W1,
                                              const float* __restrict__ W2,
                                              const float* __restrict__ Wd,
                                              unsigned short* __restrict__ WAh, unsigned short* __restrict__ WAl,
                                              unsigned short* __restrict__ WHh, unsigned short* __restrict__ WHl,
                                              unsigned short* __restrict__ WBh, unsigned short* __restrict__ WBl,
                                              unsigned short* __restrict__ WDh, unsigned short* __restrict__ WDl,
                                              float* __restrict__ Wc) {
    int i = blockIdx.x * 256 + threadIdx.x;
    const float inv = 1.0f / 63.0f;
    if (i < 3 * 65536) {
        int mat = i >> 16, j = i & 65535;
        int kq = j >> 13, r = j & 8191;
        int nb = r >> 9, r2 = r & 511;
        int l = r2 >> 3, e = r2 & 7;
        int n = nb * 16 + (l & 15);
        int k = kq * 32 + (l >> 4) * 8 + e;
        float val;
        if (mat == 0)      val = W1[k * 256 + n] - inv * W1[(256 + k) * 256 + n];
        else if (mat == 1) val = W1[(512 + k) * 256 + n];
        else               val = W2[k * 256 + n];
        unsigned short hi = f2bf(val);
        unsigned short lo = f2bf(val - bf2f(hi));
        if (mat == 0)      { WAh[j] = hi; WAl[j] = lo; }
        else if (mat == 1) { WHh[j] = hi; WHl[j] = lo; }
        else               { WBh[j] = hi; WBl[j] = lo; }
    } else if (i < 4 * 65536) {
        int j = i - 3 * 65536, k = j >> 8, n = j & 255;
        Wc[j] = inv * W1[(256 + k) * 256 + n];
    } else if (i < PREP_N) {
        int j = i - 4 * 65536, a = j >> 8, k = j & 255;
        float val = Wd[k * 16 + a];
        unsigned short hi = f2bf(val);
        WDh[j] = hi; WDl[j] = f2bf(val - bf2f(hi));
    }
}

// ---- barrier-free Karatsuba K-loop, SWAPPED roles (A=W, B=h) ----
// Wave w owns all 64 m-rows x cols [w*32, w*32+32). acc[mt 4][nt 2].
// C layout: row (n_local) = g*4+q, col (m_local) = l15 -> 4 consecutive n per thread.
__device__ __forceinline__ void kloopL2(const unsigned short* __restrict__ Wfh,
                                        const unsigned short* __restrict__ Wfl,
                                        const char* hA, f32x4 (&acc)[4][2],
                                        int w, int lane, int l15, int g)
{
    const int rxA = (l15 & 7) << 4;
    const size_t lbase = ((size_t)(w * 2) * 64 + lane) * 8;   // shorts
    #pragma unroll 2
    for (int kq = 0; kq < 8; ++kq) {
        const int cb = (kq * 64 + g * 16) ^ rxA;
        bf16x8 ah[4], al[4];
        #pragma unroll
        for (int mt = 0; mt < 4; ++mt) {
            int rb = (mt * 16 + l15) * 512;
            ah[mt] = *(const bf16x8*)(hA + rb + cb);
            al[mt] = *(const bf16x8*)(hA + HA_LO + rb + cb);
        }
        const size_t kb = (size_t)kq * 8192 + lbase;
        #pragma unroll
        for (int nt = 0; nt < 2; ++nt) {
            bf16x8 bh = *(const bf16x8*)(Wfh + kb + nt * 512);
            bf16x8 bl = *(const bf16x8*)(Wfl + kb + nt * 512);
            #pragma unroll
            for (int mt = 0; mt < 4; ++mt) {
                acc[mt][nt] = __builtin_amdgcn_mfma_f32_16x16x32_bf16(bh, ah[mt], acc[mt][nt], 0, 0, 0);
                acc[mt][nt] = __builtin_amdgcn_mfma_f32_16x16x32_bf16(bh, al[mt], acc[mt][nt], 0, 0, 0);
                acc[mt][nt] = __builtin_amdgcn_mfma_f32_16x16x32_bf16(bl, ah[mt], acc[mt][nt], 0, 0, 0);
            }
        }
    }
}

// ---- S/T: T[n] = (sum_rows h) @ Wc (512 threads; overlay region) ----
__device__ __forceinline__ void STfun(char* lds, const float* __restrict__ Wc, int tid)
{
    char* hA = lds;
    float* Sp = (float*)(lds + OV);
    float* Sf = (float*)(lds + OV + 4096);
    float* Tp = (float*)(lds + OV + 5120);
    __syncthreads();                 // hA writes visible; overlay free
    {
        int ww = tid & 127, gq = tid >> 7;
        float s0 = 0.f, s1 = 0.f;
        #pragma unroll 4
        for (int m = gq * 16; m < gq * 16 + 16; ++m) {
            int byte = m * 512 + ((ww * 4) ^ ((m & 7) << 4));
            unsigned vh = *(const unsigned*)(hA + byte);
            unsigned vl = *(const unsigned*)(hA + HA_LO + byte);
            s0 += b2f_lo(vh) + b2f_lo(vl);
            s1 += b2f_hi(vh) + b2f_hi(vl);
        }
        Sp[gq * 256 + ww * 2] = s0;
        Sp[gq * 256 + ww * 2 + 1] = s1;
    }
    __syncthreads();
    if (tid < 256) Sf[tid] = (Sp[tid] + Sp[256 + tid]) + (Sp[512 + tid] + Sp[768 + tid]);
    __syncthreads();
    {
        int n = tid & 255, kh = tid >> 8;
        float a = 0.f;
        #pragma unroll 8
        for (int k = kh * 128; k < kh * 128 + 128; ++k)
            a += Sf[k] * Wc[(k << 8) + n];
        Tp[kh * 256 + n] = a;
    }
    __syncthreads();                 // Tp visible
}

// ---- whole network, one batch per block (512 threads, 8 waves) ----
__global__ __launch_bounds__(512, 2) void fused_all(
    const int* __restrict__ ids, const float* __restrict__ emb,
    const unsigned short* __restrict__ WAh, const unsigned short* __restrict__ WAl,
    const unsigned short* __restrict__ WHh, const unsigned short* __restrict__ WHl,
    const unsigned short* __restrict__ WBh, const unsigned short* __restrict__ WBl,
    const unsigned short* __restrict__ WDh, const unsigned short* __restrict__ WDl,
    const float* __restrict__ Wc,
    const float* __restrict__ b1, const float* __restrict__ b2,
    const float* __restrict__ bd, float* __restrict__ out)
{
    __shared__ __align__(16) char lds[LDS_TOT];
    const int tid = threadIdx.x;
    const int lane = tid & 63;
    const int w = tid >> 6;              // wave owns cols [w*32, w*32+32)
    const int l15 = lane & 15, g = lane >> 4;
    const size_t rowbase = (size_t)blockIdx.x * 64;
    char* hA = lds;
    float* Tp = (float*)(lds + OV + 5120);

    // ---- stage h0 = emb[ids] -> split hi/lo, XOR-swizzled ----
    {
        int r = tid >> 3, c0 = (tid & 7) * 32;
        int rx = (r & 7) << 4;
        const float4* src = (const float4*)(emb + (size_t)ids[rowbase + r] * HID + c0);
        char* dh = hA + r * 512;
        #pragma unroll
        for (int j = 0; j < 8; ++j) {
            float4 v = src[j];
            unsigned short h0 = f2bf(v.x), h1 = f2bf(v.y), h2 = f2bf(v.z), h3 = f2bf(v.w);
            unsigned short q0 = f2bf(v.x - bf2f(h0)), q1 = f2bf(v.y - bf2f(h1)),
                           q2 = f2bf(v.z - bf2f(h2)), q3 = f2bf(v.w - bf2f(h3));
            int byte = ((c0 + j * 4) * 2) ^ rx;
            *(uint2*)(dh + byte) = make_uint2((unsigned)h0 | ((unsigned)h1 << 16),
                                             (unsigned)h2 | ((unsigned)h3 << 16));
            *(uint2*)(dh + HA_LO + byte) = make_uint2((unsigned)q0 | ((unsigned)q1 << 16),
                                                      (unsigned)q2 | ((unsigned)q3 << 16));
        }
    }

    // per-thread column bases (4 consecutive n per (nt))
    const int cb0 = w * 32 + g * 4;      // nt=0 column base
    // nt=1 base = cb0 + 16

    STfun(lds, Wc, tid);                 // entry barrier covers h0 staging
    f32x4 tvr[2];
    #pragma unroll
    for (int nt = 0; nt < 2; ++nt) {
        int col = cb0 + nt * 16;
        tvr[nt] = *(const f32x4*)(Tp + col) + *(const f32x4*)(Tp + 256 + col);
    }

    f32x4 acc[4][2], u0r[4][2];
    #pragma unroll
    for (int mt = 0; mt < 4; ++mt)
        #pragma unroll
        for (int nt = 0; nt < 2; ++nt) acc[mt][nt] = (f32x4){0.f, 0.f, 0.f, 0.f};

    for (int s = 0; s < 4; ++s) {
        if (s == 0) {
            // u0 = h0 @ W1h0 + b1  (acc starts 0; hA holds h0)
            kloopL2(WHh, WHl, hA, acc, w, lane, l15, g);
            #pragma unroll
            for (int nt = 0; nt < 2; ++nt) {
                f32x4 b1v = *(const f32x4*)(b1 + cb0 + nt * 16);
                #pragma unroll
                for (int mt = 0; mt < 4; ++mt) {
                    u0r[mt][nt] = acc[mt][nt] + b1v;
                    acc[mt][nt] = (f32x4){0.f, 0.f, 0.f, 0.f};
                }
            }
        }
        // ---- phase A: acc = T + u0, then acc += h @ Aw ----
        #pragma unroll
        for (int mt = 0; mt < 4; ++mt)
            #pragma unroll
            for (int nt = 0; nt < 2; ++nt)
                acc[mt][nt] = tvr[nt] + u0r[mt][nt];
        kloopL2(WAh, WAl, hA, acc, w, lane, l15, g);

        // ---- epilogue A (vectorized): act = relu(acc) -> hA ; acc := hres + b2 ----
        __syncthreads();                 // all phase-A hA reads done
        {
            f32x4 b2v0 = *(const f32x4*)(b2 + cb0);
            f32x4 b2v1 = *(const f32x4*)(b2 + cb0 + 16);
            #pragma unroll
            for (int mt = 0; mt < 4; ++mt)
                #pragma unroll
                for (int nt = 0; nt < 2; ++nt) {
                    int row = mt * 16 + l15;
                    int byte = row * 512 + (((cb0 + nt * 16) * 2) ^ ((l15 & 7) << 4));
                    uint2 ph = *(const uint2*)(hA + byte);
                    uint2 pl = *(const uint2*)(hA + HA_LO + byte);
                    f32x4 hres;
                    hres[0] = b2f_lo(ph.x) + b2f_lo(pl.x);
                    hres[1] = b2f_hi(ph.x) + b2f_hi(pl.x);
                    hres[2] = b2f_lo(ph.y) + b2f_lo(pl.y);
                    hres[3] = b2f_hi(ph.y) + b2f_hi(pl.y);
                    f32x4 av = acc[mt][nt];
                    float a0 = fmaxf(av[0], 0.f), a1 = fmaxf(av[1], 0.f);
                    float a2 = fmaxf(av[2], 0.f), a3 = fmaxf(av[3], 0.f);
                    unsigned h01 = pack2(a0, a1), h23 = pack2(a2, a3);
                    float r0 = a0 - bf2f((unsigned short)h01);
                    float r1 = a1 - bf2f((unsigned short)(h01 >> 16));
                    float r2 = a2 - bf2f((unsigned short)h23);
                    float r3 = a3 - bf2f((unsigned short)(h23 >> 16));
                    *(uint2*)(hA + byte) = make_uint2(h01, h23);
                    *(uint2*)(hA + HA_LO + byte) = make_uint2(pack2(r0, r1), pack2(r2, r3));
                    acc[mt][nt] = hres + (nt ? b2v1 : b2v0);
                }
        }
        __syncthreads();                 // act visible

        // ---- phase B: acc += act @ W2 ----
        kloopL2(WBh, WBl, hA, acc, w, lane, l15, g);

        // ---- epilogue B (vectorized): hnew = acc -> hA ----
        __syncthreads();                 // all phase-B reads done
        #pragma unroll
        for (int mt = 0; mt < 4; ++mt)
            #pragma unroll
            for (int nt = 0; nt < 2; ++nt) {
                int row = mt * 16 + l15;
                int byte = row * 512 + (((cb0 + nt * 16) * 2) ^ ((l15 & 7) << 4));
                f32x4 av = acc[mt][nt];
                unsigned h01 = pack2(av[0], av[1]), h23 = pack2(av[2], av[3]);
                float r0 = av[0] - bf2f((unsigned short)h01);
                float r1 = av[1] - bf2f((unsigned short)(h01 >> 16));
                float r2 = av[2] - bf2f((unsigned short)h23);
                float r3 = av[3] - bf2f((unsigned short)(h23 >> 16));
                *(uint2*)(hA + byte) = make_uint2(h01, h23);
                *(uint2*)(hA + HA_LO + byte) = make_uint2(pack2(r0, r1), pack2(r2, r3));
                acc[mt][nt] = (f32x4){0.f, 0.f, 0.f, 0.f};
            }

        if (s < 3) {
            STfun(lds, Wc, tid);          // entry barrier covers hnew writes
            #pragma unroll
            for (int nt = 0; nt < 2; ++nt) {
                int col = cb0 + nt * 16;
                tvr[nt] = *(const f32x4*)(Tp + col) + *(const f32x4*)(Tp + 256 + col);
            }
        }
    }

    // ---- decoder: waves 0-3, swapped roles -> float4 coalesced stores ----
    __syncthreads();                     // hnew visible
    if (w < 4) {
        const int rx = (l15 & 7) << 4;
        f32x4 dacc = (f32x4){0.f, 0.f, 0.f, 0.f};
        #pragma unroll 2
        for (int kq = 0; kq < 8; ++kq) {
            int byte = (w * 16 + l15) * 512 + ((kq * 64 + g * 16) ^ rx);
            bf16x8 hh = *(const bf16x8*)(hA + byte);
            bf16x8 hl = *(const bf16x8*)(hA + HA_LO + byte);
            const int k = kq * 32;
            bf16x8 wdh = *(const bf16x8*)(WDh + (size_t)l15 * 256 + k + g * 8);
            bf16x8 wdl = *(const bf16x8*)(WDl + (size_t)l15 * 256 + k + g * 8);
            dacc = __builtin_amdgcn_mfma_f32_16x16x32_bf16(wdh, hh, dacc, 0, 0, 0);
            dacc = __builtin_amdgcn_mfma_f32_16x16x32_bf16(wdh, hl, dacc, 0, 0, 0);
            dacc = __builtin_amdgcn_mfma_f32_16x16x32_bf16(wdl, hh, dacc, 0, 0, 0);
        }
        // D row = a (g*4+q), col = m (l15): lane writes logits[m][g*4..g*4+3]
        f32x4 bdv = *(const f32x4*)(bd + g * 4);
        f32x4 o = dacc + bdv;
        *(f32x4*)(out + (rowbase + w * 16 + l15) * NACT + g * 4) = o;
    }
}

extern "C" void kernel_launch(void* const* d_in, const int* in_sizes, int n_in,
                              void* d_out, int out_size, void* d_ws, size_t ws_size,
                              hipStream_t stream) {
    const int*   ids = (const int*)d_in[0];
    const float* emb = (const float*)d_in[1];
    const float* W1  = (const float*)d_in[2];
    const float* b1  = (const float*)d_in[3];
    const float* W2  = (const float*)d_in[4];
    const float* b2  = (const float*)d_in[5];
    const float* Wd  = (const float*)d_in[6];
    const float* bd  = (const float*)d_in[7];
    float* out = (float*)d_out;

    char* p = (char*)d_ws;
    unsigned short* WAh = (unsigned short*)p; p += 65536 * 2;
    unsigned short* WAl = (unsigned short*)p; p += 65536 * 2;
    unsigned short* WHh = (unsigned short*)p; p += 65536 * 2;
    unsigned short* WHl = (unsigned short*)p; p += 65536 * 2;
    unsigned short* WBh = (unsigned short*)p; p += 65536 * 2;
    unsigned short* WBl = (unsigned short*)p; p += 65536 * 2;
    unsigned short* WDh = (unsigned short*)p; p += 4096 * 2;
    unsigned short* WDl = (unsigned short*)p; p += 4096 * 2;
    float* Wc = (float*)p;

    prep_k<<<(PREP_N + 255) / 256, 256, 0, stream>>>(W1, W2, Wd, WAh, WAl, WHh, WHl,
                                                     WBh, WBl, WDh, WDl, Wc);
    fused_all<<<NB, 512, 0, stream>>>(ids, emb, WAh, WAl, WHh, WHl, WBh, WBl,
                                      WDh, WDl, Wc, b1, b2, bd, out);
}

// Round 14
// 266.178 us; speedup vs baseline: 1.0447x; 1.0447x over previous
//
#include <hip/hip_runtime.h>

#define HID 256
#define NB 1024
#define NACT 16
#define HSTRIDE 528          // 33*16B: row base advances 1 bank-quad per row

typedef __bf16 bf16x8 __attribute__((ext_vector_type(8)));
typedef float  f32x4  __attribute__((ext_vector_type(4)));

// LDS: hA hi [0,33792) | hA lo [33792,67584) | S f32[256] @67584. Total 68.6 KB.
#define HA_LO   33792
#define S_OFF   67584
#define LDS_TOT 68608

#define PREP_N (4 * 65536 + 4096)

__device__ __forceinline__ unsigned short f2bf(float x) {
    union { __bf16 b; unsigned short u; } v; v.b = (__bf16)x; return v.u;
}
__device__ __forceinline__ float bf2f(unsigned short u) {
    union { unsigned short u; __bf16 b; } v; v.u = u; return (float)v.b;
}
__device__ __forceinline__ float b2f_lo(unsigned v) { return bf2f((unsigned short)(v & 0xffffu)); }
__device__ __forceinline__ float b2f_hi(unsigned v) { return bf2f((unsigned short)(v >> 16)); }
__device__ __forceinline__ unsigned pack2(float a, float b) {
    return (unsigned)f2bf(a) | ((unsigned)f2bf(b) << 16);
}

// ---- prep: WA/WH/WB/WC in MFMA FRAGMENT ORDER [kq][nb][lane][8] (hi/lo);
//      WD [a=16][k=256] pairs. frag elem: n = nb*16+(l&15), k = kq*32+(l>>4)*8+e ----
__global__ __launch_bounds__(256) void prep_k(const float* __restrict__ W1,
                                              const float* __restrict__ W2,
                                              const float* __restrict__ Wd,
                                              unsigned short* __restrict__ WAh, unsigned short* __restrict__ WAl,
                                              unsigned short* __restrict__ WHh, unsigned short* __restrict__ WHl,
                                              unsigned short* __restrict__ WBh, unsigned short* __restrict__ WBl,
                                              unsigned short* __restrict__ WCh, unsigned short* __restrict__ WCl,
                                              unsigned short* __restrict__ WDh, unsigned short* __restrict__ WDl) {
    int i = blockIdx.x * 256 + threadIdx.x;
    const float inv = 1.0f / 63.0f;
    if (i < 4 * 65536) {
        int mat = i >> 16, j = i & 65535;
        int kq = j >> 13, r = j & 8191;
        int nb = r >> 9, r2 = r & 511;
        int l = r2 >> 3, e = r2 & 7;
        int n = nb * 16 + (l & 15);
        int k = kq * 32 + (l >> 4) * 8 + e;
        float val;
        if (mat == 0)      val = W1[k * 256 + n] - inv * W1[(256 + k) * 256 + n];
        else if (mat == 1) val = W1[(512 + k) * 256 + n];
        else if (mat == 2) val = W2[k * 256 + n];
        else               val = inv * W1[(256 + k) * 256 + n];
        unsigned short hi = f2bf(val);
        unsigned short lo = f2bf(val - bf2f(hi));
        if (mat == 0)      { WAh[j] = hi; WAl[j] = lo; }
        else if (mat == 1) { WHh[j] = hi; WHl[j] = lo; }
        else if (mat == 2) { WBh[j] = hi; WBl[j] = lo; }
        else               { WCh[j] = hi; WCl[j] = lo; }
    } else if (i < PREP_N) {
        int j = i - 4 * 65536, a = j >> 8, k = j & 255;
        float val = Wd[k * 16 + a];
        unsigned short hi = f2bf(val);
        WDh[j] = hi; WDl[j] = f2bf(val - bf2f(hi));
    }
}

// ---- barrier-free Karatsuba K-loop, swapped roles (A=W-frag, B=h-frag) ----
// Wave w owns cols [w*32, w*32+32), all 64 m-rows. acc[mt 4][nt 2].
// C layout: row(n_local) = g*4+q, col(m) = l15.
__device__ __forceinline__ void kloopL2(const unsigned short* __restrict__ Wfh,
                                        const unsigned short* __restrict__ Wfl,
                                        const char* hA, f32x4 (&acc)[4][2],
                                        size_t lbase, int l15, int g)
{
    #pragma unroll 2
    for (int kq = 0; kq < 8; ++kq) {
        const int cb = kq * 64 + g * 16;
        bf16x8 ah[4], al[4];
        #pragma unroll
        for (int mt = 0; mt < 4; ++mt) {
            int rb = (mt * 16 + l15) * HSTRIDE;
            ah[mt] = *(const bf16x8*)(hA + rb + cb);
            al[mt] = *(const bf16x8*)(hA + HA_LO + rb + cb);
        }
        const size_t kb = (size_t)kq * 8192 + lbase;
        #pragma unroll
        for (int nt = 0; nt < 2; ++nt) {
            bf16x8 bh = *(const bf16x8*)(Wfh + kb + nt * 512);
            bf16x8 bl = *(const bf16x8*)(Wfl + kb + nt * 512);
            #pragma unroll
            for (int mt = 0; mt < 4; ++mt) {
                acc[mt][nt] = __builtin_amdgcn_mfma_f32_16x16x32_bf16(bh, ah[mt], acc[mt][nt], 0, 0, 0);
                acc[mt][nt] = __builtin_amdgcn_mfma_f32_16x16x32_bf16(bh, al[mt], acc[mt][nt], 0, 0, 0);
                acc[mt][nt] = __builtin_amdgcn_mfma_f32_16x16x32_bf16(bl, ah[mt], acc[mt][nt], 0, 0, 0);
            }
        }
    }
}

// ---- whole network, one batch per block (512 threads, 8 waves) ----
__global__ __launch_bounds__(512, 2) void fused_all(
    const int* __restrict__ ids, const float* __restrict__ emb,
    const unsigned short* __restrict__ WAh, const unsigned short* __restrict__ WAl,
    const unsigned short* __restrict__ WHh, const unsigned short* __restrict__ WHl,
    const unsigned short* __restrict__ WBh, const unsigned short* __restrict__ WBl,
    const unsigned short* __restrict__ WCh, const unsigned short* __restrict__ WCl,
    const unsigned short* __restrict__ WDh, const unsigned short* __restrict__ WDl,
    const float* __restrict__ b1, const float* __restrict__ b2,
    const float* __restrict__ bd, float* __restrict__ out)
{
    __shared__ __align__(16) char lds[LDS_TOT];
    const int tid = threadIdx.x;
    const int lane = tid & 63;
    const int w = tid >> 6;              // wave owns cols [w*32, w*32+32)
    const int l15 = lane & 15, g = lane >> 4;
    const size_t rowbase = (size_t)blockIdx.x * 64;
    char* hA = lds;
    float* Sf = (float*)(lds + S_OFF);
    const size_t lbase = ((size_t)(w * 2) * 64 + lane) * 8;
    const int cb0 = w * 32 + g * 4;      // nt=0 column base

    // ---- stage h0 = emb[ids] -> split hi/lo, 528-stride ----
    {
        int r = tid >> 3, c0 = (tid & 7) * 32;
        const float4* src = (const float4*)(emb + (size_t)ids[rowbase + r] * HID + c0);
        char* dh = hA + r * HSTRIDE + c0 * 2;
        #pragma unroll
        for (int j = 0; j < 8; ++j) {
            float4 v = src[j];
            unsigned short h0 = f2bf(v.x), h1 = f2bf(v.y), h2 = f2bf(v.z), h3 = f2bf(v.w);
            unsigned short q0 = f2bf(v.x - bf2f(h0)), q1 = f2bf(v.y - bf2f(h1)),
                           q2 = f2bf(v.z - bf2f(h2)), q3 = f2bf(v.w - bf2f(h3));
            *(uint2*)(dh + j * 8) = make_uint2((unsigned)h0 | ((unsigned)h1 << 16),
                                               (unsigned)h2 | ((unsigned)h3 << 16));
            *(uint2*)(dh + HA_LO + j * 8) = make_uint2((unsigned)q0 | ((unsigned)q1 << 16),
                                                       (unsigned)q2 | ((unsigned)q3 << 16));
        }
    }
    __syncthreads();

    // ---- S0: column sums of h0 (one-time) ----
    if (tid < 256) {
        float ssum = 0.f;
        #pragma unroll 8
        for (int m = 0; m < 64; ++m) {
            int byte = m * HSTRIDE + tid * 2;
            ssum += bf2f(*(const unsigned short*)(hA + byte))
                  + bf2f(*(const unsigned short*)(hA + HA_LO + byte));
        }
        Sf[tid] = ssum;
    }
    __syncthreads();

    f32x4 acc[4][2], u0r[4][2];
    #pragma unroll
    for (int mt = 0; mt < 4; ++mt)
        #pragma unroll
        for (int nt = 0; nt < 2; ++nt) acc[mt][nt] = (f32x4){0.f, 0.f, 0.f, 0.f};

    // ---- u0 = h0 @ W1h0 + b1 ----
    kloopL2(WHh, WHl, hA, acc, lbase, l15, g);
    #pragma unroll
    for (int nt = 0; nt < 2; ++nt) {
        f32x4 b1v = *(const f32x4*)(b1 + cb0 + nt * 16);
        #pragma unroll
        for (int mt = 0; mt < 4; ++mt)
            u0r[mt][nt] = acc[mt][nt] + b1v;
    }

    for (int s = 0; s < 4; ++s) {
        // ---- T via split-bf16 MFMA: tacc[nt] = S @ Wc (swapped roles, Karatsuba) ----
        f32x4 tacc[2];
        tacc[0] = tacc[1] = (f32x4){0.f, 0.f, 0.f, 0.f};
        #pragma unroll 2
        for (int kq = 0; kq < 8; ++kq) {
            const float* sp = Sf + kq * 32 + g * 8;
            f32x4 sa = *(const f32x4*)sp;
            f32x4 sb = *(const f32x4*)(sp + 4);
            bf16x8 shv, slv;
            #pragma unroll
            for (int e = 0; e < 8; ++e) {
                float sv = (e < 4) ? sa[e] : sb[e - 4];
                unsigned short h = f2bf(sv);
                ((unsigned short*)&shv)[e] = h;
                ((unsigned short*)&slv)[e] = f2bf(sv - bf2f(h));
            }
            const size_t kb = (size_t)kq * 8192 + lbase;
            #pragma unroll
            for (int nt = 0; nt < 2; ++nt) {
                bf16x8 wch = *(const bf16x8*)(WCh + kb + nt * 512);
                bf16x8 wcl = *(const bf16x8*)(WCl + kb + nt * 512);
                tacc[nt] = __builtin_amdgcn_mfma_f32_16x16x32_bf16(wch, shv, tacc[nt], 0, 0, 0);
                tacc[nt] = __builtin_amdgcn_mfma_f32_16x16x32_bf16(wch, slv, tacc[nt], 0, 0, 0);
                tacc[nt] = __builtin_amdgcn_mfma_f32_16x16x32_bf16(wcl, shv, tacc[nt], 0, 0, 0);
            }
        }

        // ---- phase A: acc = u0 + T, then acc += h @ Aw ----
        #pragma unroll
        for (int mt = 0; mt < 4; ++mt)
            #pragma unroll
            for (int nt = 0; nt < 2; ++nt)
                acc[mt][nt] = u0r[mt][nt] + tacc[nt];
        kloopL2(WAh, WAl, hA, acc, lbase, l15, g);

        // ---- epilogue A: act = relu(acc) -> hA ; acc := hres + b2 ----
        __syncthreads();                 // all phase-A hA reads done
        {
            f32x4 b2v0 = *(const f32x4*)(b2 + cb0);
            f32x4 b2v1 = *(const f32x4*)(b2 + cb0 + 16);
            #pragma unroll
            for (int mt = 0; mt < 4; ++mt)
                #pragma unroll
                for (int nt = 0; nt < 2; ++nt) {
                    int byte = (mt * 16 + l15) * HSTRIDE + (cb0 + nt * 16) * 2;
                    uint2 ph = *(const uint2*)(hA + byte);
                    uint2 pl = *(const uint2*)(hA + HA_LO + byte);
                    f32x4 hres;
                    hres[0] = b2f_lo(ph.x) + b2f_lo(pl.x);
                    hres[1] = b2f_hi(ph.x) + b2f_hi(pl.x);
                    hres[2] = b2f_lo(ph.y) + b2f_lo(pl.y);
                    hres[3] = b2f_hi(ph.y) + b2f_hi(pl.y);
                    f32x4 av = acc[mt][nt];
                    float a0 = fmaxf(av[0], 0.f), a1 = fmaxf(av[1], 0.f);
                    float a2 = fmaxf(av[2], 0.f), a3 = fmaxf(av[3], 0.f);
                    unsigned h01 = pack2(a0, a1), h23 = pack2(a2, a3);
                    float r0 = a0 - bf2f((unsigned short)h01);
                    float r1 = a1 - bf2f((unsigned short)(h01 >> 16));
                    float r2 = a2 - bf2f((unsigned short)h23);
                    float r3 = a3 - bf2f((unsigned short)(h23 >> 16));
                    *(uint2*)(hA + byte) = make_uint2(h01, h23);
                    *(uint2*)(hA + HA_LO + byte) = make_uint2(pack2(r0, r1), pack2(r2, r3));
                    acc[mt][nt] = hres + (nt ? b2v1 : b2v0);
                }
        }
        __syncthreads();                 // act visible

        // ---- phase B: acc += act @ W2 ----
        kloopL2(WBh, WBl, hA, acc, lbase, l15, g);

        // ---- epilogue B: hnew = acc -> hA ; fold rowsum S for next step ----
        __syncthreads();                 // all phase-B reads done
        #pragma unroll
        for (int mt = 0; mt < 4; ++mt)
            #pragma unroll
            for (int nt = 0; nt < 2; ++nt) {
                int byte = (mt * 16 + l15) * HSTRIDE + (cb0 + nt * 16) * 2;
                f32x4 av = acc[mt][nt];
                unsigned h01 = pack2(av[0], av[1]), h23 = pack2(av[2], av[3]);
                float r0 = av[0] - bf2f((unsigned short)h01);
                float r1 = av[1] - bf2f((unsigned short)(h01 >> 16));
                float r2 = av[2] - bf2f((unsigned short)h23);
                float r3 = av[3] - bf2f((unsigned short)(h23 >> 16));
                *(uint2*)(hA + byte) = make_uint2(h01, h23);
                *(uint2*)(hA + HA_LO + byte) = make_uint2(pack2(r0, r1), pack2(r2, r3));
            }
        if (s < 3) {
            #pragma unroll
            for (int nt = 0; nt < 2; ++nt) {
                f32x4 cs = (acc[0][nt] + acc[1][nt]) + (acc[2][nt] + acc[3][nt]);
                #pragma unroll
                for (int d = 1; d < 16; d <<= 1) {
                    cs[0] += __shfl_xor(cs[0], d);
                    cs[1] += __shfl_xor(cs[1], d);
                    cs[2] += __shfl_xor(cs[2], d);
                    cs[3] += __shfl_xor(cs[3], d);
                }
                if (l15 == 0) *(f32x4*)(Sf + cb0 + nt * 16) = cs;
            }
        }
        __syncthreads();                 // hnew + S visible
    }

    // ---- decoder: waves 0-3, swapped roles -> float4 coalesced stores ----
    if (w < 4) {
        f32x4 dacc = (f32x4){0.f, 0.f, 0.f, 0.f};
        #pragma unroll 2
        for (int kq = 0; kq < 8; ++kq) {
            int byte = (w * 16 + l15) * HSTRIDE + kq * 64 + g * 16;
            bf16x8 hh = *(const bf16x8*)(hA + byte);
            bf16x8 hl = *(const bf16x8*)(hA + HA_LO + byte);
            const int k = kq * 32;
            bf16x8 wdh = *(const bf16x8*)(WDh + (size_t)l15 * 256 + k + g * 8);
            bf16x8 wdl = *(const bf16x8*)(WDl + (size_t)l15 * 256 + k + g * 8);
            dacc = __builtin_amdgcn_mfma_f32_16x16x32_bf16(wdh, hh, dacc, 0, 0, 0);
            dacc = __builtin_amdgcn_mfma_f32_16x16x32_bf16(wdh, hl, dacc, 0, 0, 0);
            dacc = __builtin_amdgcn_mfma_f32_16x16x32_bf16(wdl, hh, dacc, 0, 0, 0);
        }
        f32x4 bdv = *(const f32x4*)(bd + g * 4);
        f32x4 o = dacc + bdv;
        *(f32x4*)(out + (rowbase + w * 16 + l15) * NACT + g * 4) = o;
    }
}

extern "C" void kernel_launch(void* const* d_in, const int* in_sizes, int n_in,
                              void* d_out, int out_size, void* d_ws, size_t ws_size,
                              hipStream_t stream) {
    const int*   ids = (const int*)d_in[0];
    const float* emb = (const float*)d_in[1];
    const float* W1  = (const float*)d_in[2];
    const float* b1  = (const float*)d_in[3];
    const float* W2  = (const float*)d_in[4];
    const float* b2  = (const float*)d_in[5];
    const float* Wd  = (const float*)d_in[6];
    const float* bd  = (const float*)d_in[7];
    float* out = (float*)d_out;

    char* p = (char*)d_ws;
    unsigned short* WAh = (unsigned short*)p; p += 65536 * 2;
    unsigned short* WAl = (unsigned short*)p; p += 65536 * 2;
    unsigned short* WHh = (unsigned short*)p; p += 65536 * 2;
    unsigned short* WHl = (unsigned short*)p; p += 65536 * 2;
    unsigned short* WBh = (unsigned short*)p; p += 65536 * 2;
    unsigned short* WBl = (unsigned short*)p; p += 65536 * 2;
    unsigned short* WCh = (unsigned short*)p; p += 65536 * 2;
    unsigned short* WCl = (unsigned short*)p; p += 65536 * 2;
    unsigned short* WDh = (unsigned short*)p; p += 4096 * 2;
    unsigned short* WDl = (unsigned short*)p; p += 4096 * 2;

    prep_k<<<(PREP_N + 255) / 256, 256, 0, stream>>>(W1, W2, Wd, WAh, WAl, WHh, WHl,
                                                     WBh, WBl, WCh, WCl, WDh, WDl);
    fused_all<<<NB, 512, 0, stream>>>(ids, emb, WAh, WAl, WHh, WHl, WBh, WBl,
                                      WCh, WCl, WDh, WDl, b1, b2, bd, out);
}